// Round 2
// baseline (777.147 us; speedup 1.0000x reference)
//
#include <hip/hip_runtime.h>

typedef unsigned short u16;
typedef unsigned short u16x8 __attribute__((ext_vector_type(8)));
typedef short s16x8 __attribute__((ext_vector_type(8)));
typedef float f32x4 __attribute__((ext_vector_type(4)));

__device__ __forceinline__ float b2f(u16 u) {
    return __builtin_bit_cast(float, (unsigned)u << 16);
}
__device__ __forceinline__ u16 f2bf(float f) {
    unsigned x = __builtin_bit_cast(unsigned, f);
    return (u16)((x + 0x7fffu + ((x >> 16) & 1u)) >> 16);
}
__device__ __forceinline__ float gelu_f(float x) {
    float t = tanhf(0.7978845608028654f * (x + 0.044715f * x * x * x));
    return 0.5f * x * (1.0f + t);
}
__device__ __forceinline__ f32x4 mfma16(s16x8 a, s16x8 b, f32x4 c) {
    return __builtin_amdgcn_mfma_f32_16x16x32_bf16(a, b, c, 0, 0, 0);
}

// ------- transpose+cast: in f32 [K][N] -> out bf16 [N][K]; K,N mult of 64 ----
__global__ __launch_bounds__(256) void transpose_k(const float* __restrict__ in,
                                                   u16* __restrict__ out,
                                                   int K, int N) {
    __shared__ u16 tile[64][72];
    int k0 = blockIdx.y << 6, n0 = blockIdx.x << 6;
    int tid = threadIdx.x;
    int r = tid >> 2, c = (tid & 3) << 4;  // r 0..63, c in {0,16,32,48}
    const float* ip = in + (size_t)(k0 + r) * N + n0 + c;
#pragma unroll
    for (int q = 0; q < 4; ++q) {
        f32x4 v = *(const f32x4*)(ip + 4 * q);
#pragma unroll
        for (int e = 0; e < 4; ++e) tile[r][c + 4 * q + e] = f2bf(v[e]);
    }
    __syncthreads();
    u16x8 o0, o1;
#pragma unroll
    for (int e = 0; e < 8; ++e) { o0[e] = tile[c + e][r]; o1[e] = tile[c + 8 + e][r]; }
    u16* op = out + (size_t)(n0 + r) * K + k0 + c;
    *(u16x8*)op = o0;
    *(u16x8*)(op + 8) = o1;
}

// ------- LayerNorm over D=768: f32 in, bf16 out; one block per row ----------
__global__ __launch_bounds__(256) void ln_k(const float* __restrict__ in,
                                            const float* __restrict__ g,
                                            const float* __restrict__ be,
                                            u16* __restrict__ out) {
    int row = blockIdx.x, tid = threadIdx.x;
    const float* p = in + (size_t)row * 768;
    float v0 = p[tid], v1 = p[tid + 256], v2 = p[tid + 512];
    float s = v0 + v1 + v2;
    float q = v0 * v0 + v1 * v1 + v2 * v2;
#pragma unroll
    for (int m = 1; m < 64; m <<= 1) { s += __shfl_xor(s, m); q += __shfl_xor(q, m); }
    __shared__ float red[8];
    int w = tid >> 6, lane = tid & 63;
    if (lane == 0) { red[w] = s; red[4 + w] = q; }
    __syncthreads();
    s = red[0] + red[1] + red[2] + red[3];
    q = red[4] + red[5] + red[6] + red[7];
    float mean = s * (1.0f / 768.0f);
    float var = q * (1.0f / 768.0f) - mean * mean;
    float rstd = rsqrtf(var + 1e-6f);
    u16* o = out + (size_t)row * 768;
    o[tid]       = f2bf((v0 - mean) * rstd * g[tid]       + be[tid]);
    o[tid + 256] = f2bf((v1 - mean) * rstd * g[tid + 256] + be[tid + 256]);
    o[tid + 512] = f2bf((v2 - mean) * rstd * g[tid + 512] + be[tid + 512]);
}

// ------- blend: a = w1*a + w2*b (bf16, 8-wide) -------------------------------
__global__ __launch_bounds__(256) void blend_k(u16* __restrict__ a,
                                               const u16* __restrict__ b,
                                               const float* w1, const float* w2,
                                               int n8) {
    float wa = *w1, wb = *w2;
    for (int i = blockIdx.x * blockDim.x + threadIdx.x; i < n8;
         i += gridDim.x * blockDim.x) {
        u16x8 va = ((const u16x8*)a)[i];
        u16x8 vb = ((const u16x8*)b)[i];
        u16x8 r;
#pragma unroll
        for (int e = 0; e < 8; ++e) r[e] = f2bf(wa * b2f(va[e]) + wb * b2f(vb[e]));
        ((u16x8*)a)[i] = r;
    }
}

// ------- GEMM: C = A[M,K](bf16) @ BT[N,K](bf16); bias f32 --------------------
// EPI_PLAIN: += resid(f32), store f32.  EPI_GELU: gelu, store bf16.
// EPI_QK / EPI_VT: head-split stores, bf16.
#define EPI_PLAIN 0
#define EPI_QK 1
#define EPI_VT 2
#define EPI_GELU 3

template <int EPI>
__global__ __launch_bounds__(256) void gemm_k(const u16* __restrict__ A,
                                              const u16* __restrict__ BT,
                                              const float* __restrict__ bias,
                                              const float* __restrict__ resid,
                                              const float* sc1, const float* sc2,
                                              void* __restrict__ Cv,
                                              int M, int N, int K) {
    float* Cf = (float*)Cv;
    u16* Cb = (u16*)Cv;
    __shared__ u16 lA[64][40];
    __shared__ u16 lB[64][40];
    int tid = threadIdx.x;
    int bm0 = blockIdx.y << 6, bn0 = blockIdx.x << 6;
    int lane = tid & 63, wid = tid >> 6, wm = wid >> 1, wn = wid & 1;
    int sr = tid >> 2, sc = (tid & 3) << 3;
    const u16* ap = A + (size_t)(bm0 + sr) * K + sc;
    const u16* bp = BT + (size_t)(bn0 + sr) * K + sc;
    f32x4 acc[2][2] = {};
    int ar = (lane & 15), ko = (lane >> 4) << 3;
    for (int k0 = 0; k0 < K; k0 += 32) {
        u16x8 av = *(const u16x8*)(ap + k0);
        u16x8 bv = *(const u16x8*)(bp + k0);
        __syncthreads();
        *(u16x8*)&lA[sr][sc] = av;
        *(u16x8*)&lB[sr][sc] = bv;
        __syncthreads();
        s16x8 am0 = *(const s16x8*)&lA[wm * 32 + ar][ko];
        s16x8 am1 = *(const s16x8*)&lA[wm * 32 + 16 + ar][ko];
        s16x8 bn0f = *(const s16x8*)&lB[wn * 32 + ar][ko];
        s16x8 bn1f = *(const s16x8*)&lB[wn * 32 + 16 + ar][ko];
        acc[0][0] = mfma16(am0, bn0f, acc[0][0]);
        acc[0][1] = mfma16(am0, bn1f, acc[0][1]);
        acc[1][0] = mfma16(am1, bn0f, acc[1][0]);
        acc[1][1] = mfma16(am1, bn1f, acc[1][1]);
    }
    float bscale = 1.0f;
    if (sc1) bscale = sc1[0] + sc2[0];
#pragma unroll
    for (int j = 0; j < 2; ++j) {
        int n = bn0 + wn * 32 + j * 16 + (lane & 15);
        float bv = bias ? bias[n] * bscale : 0.0f;
#pragma unroll
        for (int i = 0; i < 2; ++i) {
#pragma unroll
            for (int r = 0; r < 4; ++r) {
                int m = bm0 + wm * 32 + i * 16 + ((lane >> 4) << 2) + r;
                float v = acc[i][j][r] + bv;
                if (EPI == EPI_PLAIN) {
                    if (resid) v += resid[(size_t)m * N + n];
                    Cf[(size_t)m * N + n] = v;
                } else if (EPI == EPI_GELU) {
                    Cb[(size_t)m * N + n] = f2bf(gelu_f(v));
                } else {
                    int bb = m >> 10, ss = m & 1023, hh = n >> 6, hd = n & 63;
                    size_t o = ((size_t)(bb * 12 + hh)) << 16;
                    if (EPI == EPI_QK) o += ((size_t)ss << 6) + hd;
                    else               o += ((size_t)hd << 10) + ss;
                    Cb[o] = f2bf(v);
                }
            }
        }
    }
}

// ------- fused attention: 4 configs, flash-style (all bf16, f32 accum) -------
// Q,K: [B,H,S,64] ; VT: [B,H,64,S] ; out ctx: [B,S,768] bf16
__global__ __launch_bounds__(256) void attn_k(const u16* __restrict__ Qx,
                                              const u16* __restrict__ Kx,
                                              const u16* __restrict__ VTx,
                                              const u16* __restrict__ Qy,
                                              const u16* __restrict__ Ky,
                                              const u16* __restrict__ VTy,
                                              u16* __restrict__ csx,
                                              u16* __restrict__ ccx,
                                              u16* __restrict__ csy,
                                              u16* __restrict__ ccy) {
    int bid = blockIdx.x;
    int cfg = bid / (48 * 16);
    int rem = bid % (48 * 16);
    int bh = rem / 16, qt = rem % 16;
    const u16 *Qp, *Kp, *Vp;
    u16* Op;
    if (cfg == 0)      { Qp = Qx; Kp = Kx; Vp = VTx; Op = csx; }
    else if (cfg == 1) { Qp = Qy; Kp = Ky; Vp = VTy; Op = csy; }
    else if (cfg == 2) { Qp = Qx; Kp = Ky; Vp = VTy; Op = ccx; }
    else               { Qp = Qy; Kp = Kx; Vp = VTx; Op = ccy; }
    const u16* Qh = Qp + ((size_t)bh << 16);
    const u16* Kh = Kp + ((size_t)bh << 16);
    const u16* Vh = Vp + ((size_t)bh << 16);
    int b = bh / 12, h = bh % 12;
    int tid = threadIdx.x, lane = tid & 63, w = tid >> 6;
    int q0 = qt * 64 + w * 16;
    int ko = (lane >> 4) << 3;  // 0,8,16,24

    const u16* qp = Qh + (size_t)(q0 + (lane & 15)) * 64 + ko;
    s16x8 qf0 = *(const s16x8*)qp;
    s16x8 qf1 = *(const s16x8*)(qp + 32);

    f32x4 acc[4] = {};
    float mr[4] = {-1e30f, -1e30f, -1e30f, -1e30f};
    float lr[4] = {0.f, 0.f, 0.f, 0.f};
    __shared__ u16 pbuf[4][16][40];
    f32x4 zz = {0.f, 0.f, 0.f, 0.f};

    for (int kb = 0; kb < 1024; kb += 32) {
        const u16* kp0 = Kh + (size_t)(kb + (lane & 15)) * 64 + ko;
        const u16* kp1 = Kh + (size_t)(kb + 16 + (lane & 15)) * 64 + ko;
        s16x8 k00 = *(const s16x8*)kp0;
        s16x8 k01 = *(const s16x8*)(kp0 + 32);
        s16x8 k10 = *(const s16x8*)kp1;
        s16x8 k11 = *(const s16x8*)(kp1 + 32);
        f32x4 s0 = mfma16(qf0, k00, zz);
        s0 = mfma16(qf1, k01, s0);
        f32x4 s1 = mfma16(qf0, k10, zz);
        s1 = mfma16(qf1, k11, s1);
        float fac[4];
#pragma unroll
        for (int r = 0; r < 4; ++r) {
            float a0 = s0[r] * 0.125f, a1 = s1[r] * 0.125f;
            float t = fmaxf(a0, a1);
            t = fmaxf(t, __shfl_xor(t, 1));
            t = fmaxf(t, __shfl_xor(t, 2));
            t = fmaxf(t, __shfl_xor(t, 4));
            t = fmaxf(t, __shfl_xor(t, 8));
            float mn = fmaxf(mr[r], t);
            fac[r] = __expf(mr[r] - mn);
            float p0 = __expf(a0 - mn), p1 = __expf(a1 - mn);
            float rs = p0 + p1;
            rs += __shfl_xor(rs, 1);
            rs += __shfl_xor(rs, 2);
            rs += __shfl_xor(rs, 4);
            rs += __shfl_xor(rs, 8);
            lr[r] = lr[r] * fac[r] + rs;
            mr[r] = mn;
            int prow = ((lane >> 4) << 2) + r;
            pbuf[w][prow][lane & 15] = f2bf(p0);
            pbuf[w][prow][16 + (lane & 15)] = f2bf(p1);
        }
#pragma unroll
        for (int t4 = 0; t4 < 4; ++t4) {
#pragma unroll
            for (int r = 0; r < 4; ++r) acc[t4][r] *= fac[r];
        }
        asm volatile("s_waitcnt lgkmcnt(0)" ::: "memory");
        s16x8 pa = *(const s16x8*)&pbuf[w][lane & 15][ko];
#pragma unroll
        for (int t4 = 0; t4 < 4; ++t4) {
            const u16* vp = Vh + (size_t)(t4 * 16 + (lane & 15)) * 1024 + kb + ko;
            s16x8 vf = *(const s16x8*)vp;
            acc[t4] = mfma16(pa, vf, acc[t4]);
        }
    }
    float inv[4];
#pragma unroll
    for (int r = 0; r < 4; ++r) inv[r] = 1.0f / lr[r];
    u16* ob = Op + (size_t)(b * 1024 + q0 + ((lane >> 4) << 2)) * 768 + h * 64 + (lane & 15);
#pragma unroll
    for (int t4 = 0; t4 < 4; ++t4) {
#pragma unroll
        for (int r = 0; r < 4; ++r) ob[(size_t)r * 768 + t4 * 16] = f2bf(acc[t4][r] * inv[r]);
    }
}

// -----------------------------------------------------------------------------
extern "C" void kernel_launch(void* const* d_in, const int* in_sizes, int n_in,
                              void* d_out, int out_size, void* d_ws, size_t ws_size,
                              hipStream_t stream) {
    (void)in_sizes; (void)n_in; (void)out_size; (void)ws_size;
    const float* X    = (const float*)d_in[0];
    const float* Y    = (const float*)d_in[1];
    const float* l1xg = (const float*)d_in[2];
    const float* l1xb = (const float*)d_in[3];
    const float* l1yg = (const float*)d_in[4];
    const float* l1yb = (const float*)d_in[5];
    const float* Wq   = (const float*)d_in[6];
    const float* bq   = (const float*)d_in[7];
    const float* Wk   = (const float*)d_in[8];
    const float* bk   = (const float*)d_in[9];
    const float* Wv   = (const float*)d_in[10];
    const float* bv   = (const float*)d_in[11];
    const float* Wo   = (const float*)d_in[12];
    const float* bo   = (const float*)d_in[13];
    const float* Wqd  = (const float*)d_in[14];
    const float* bqd  = (const float*)d_in[15];
    const float* Wkd  = (const float*)d_in[16];
    const float* bkd  = (const float*)d_in[17];
    const float* Wvd  = (const float*)d_in[18];
    const float* bvd  = (const float*)d_in[19];
    const float* Wod  = (const float*)d_in[20];
    const float* bod  = (const float*)d_in[21];
    const float* w11  = (const float*)d_in[22];
    const float* w12  = (const float*)d_in[23];
    const float* w21  = (const float*)d_in[24];
    const float* w22  = (const float*)d_in[25];
    const float* l2xg = (const float*)d_in[26];
    const float* l2xb = (const float*)d_in[27];
    const float* l2yg = (const float*)d_in[28];
    const float* l2yb = (const float*)d_in[29];
    const float* W1   = (const float*)d_in[30];
    const float* b1   = (const float*)d_in[31];
    const float* W2   = (const float*)d_in[32];
    const float* b2   = (const float*)d_in[33];
    const float* W1d  = (const float*)d_in[34];
    const float* b1d  = (const float*)d_in[35];
    const float* W2d  = (const float*)d_in[36];
    const float* b2d  = (const float*)d_in[37];

    const size_t E = (size_t)4096 * 768;
    const size_t DD = (size_t)768 * 768, DF = (size_t)768 * 3072;
    u16* ws = (u16*)d_ws;
    // bf16 weight transposes (persist whole launch)
    u16 *WqT = ws, *WkT = WqT + DD, *WvT = WkT + DD, *WoT = WvT + DD;
    u16 *WqdT = WoT + DD, *WkdT = WqdT + DD, *WvdT = WkdT + DD, *WodT = WvdT + DD;
    u16 *W1T = WodT + DD, *W2T = W1T + DF, *W1dT = W2T + DF, *W2dT = W1dT + DF;
    u16* buf = W2dT + DF;
    u16 *xn = buf, *yn = xn + E;
    u16 *Qx = yn + E, *Kx = Qx + E, *VTx = Kx + E;
    u16 *Qy = VTx + E, *Ky = Qy + E, *VTy = Ky + E;
    u16* h = Qx;  // alias: QKV dead after attention+blends; h = 4096x3072 bf16 (4E <= 6E)
    u16 *csx = VTy + E, *ccx = csx + E, *csy = ccx + E, *ccy = csy + E;
    float* x1 = (float*)(ccy + E);
    float* y1 = x1 + E;

    float* out_x = (float*)d_out;
    float* out_y = out_x + E;

    dim3 tb(256);
    // weight transposes + bf16 cast
    transpose_k<<<dim3(12, 12), tb, 0, stream>>>(Wq, WqT, 768, 768);
    transpose_k<<<dim3(12, 12), tb, 0, stream>>>(Wk, WkT, 768, 768);
    transpose_k<<<dim3(12, 12), tb, 0, stream>>>(Wv, WvT, 768, 768);
    transpose_k<<<dim3(12, 12), tb, 0, stream>>>(Wo, WoT, 768, 768);
    transpose_k<<<dim3(12, 12), tb, 0, stream>>>(Wqd, WqdT, 768, 768);
    transpose_k<<<dim3(12, 12), tb, 0, stream>>>(Wkd, WkdT, 768, 768);
    transpose_k<<<dim3(12, 12), tb, 0, stream>>>(Wvd, WvdT, 768, 768);
    transpose_k<<<dim3(12, 12), tb, 0, stream>>>(Wod, WodT, 768, 768);
    transpose_k<<<dim3(48, 12), tb, 0, stream>>>(W1, W1T, 768, 3072);
    transpose_k<<<dim3(12, 48), tb, 0, stream>>>(W2, W2T, 3072, 768);
    transpose_k<<<dim3(48, 12), tb, 0, stream>>>(W1d, W1dT, 768, 3072);
    transpose_k<<<dim3(12, 48), tb, 0, stream>>>(W2d, W2dT, 3072, 768);
    // LN1 (f32 in -> bf16 out)
    ln_k<<<4096, tb, 0, stream>>>(X, l1xg, l1xb, xn);
    ln_k<<<4096, tb, 0, stream>>>(Y, l1yg, l1yb, yn);
    // QKV projections (head-split bf16 stores; V transposed)
    dim3 gDD(12, 64);
    gemm_k<EPI_QK><<<gDD, tb, 0, stream>>>(xn, WqT, bq, nullptr, nullptr, nullptr, Qx, 4096, 768, 768);
    gemm_k<EPI_QK><<<gDD, tb, 0, stream>>>(xn, WkT, bk, nullptr, nullptr, nullptr, Kx, 4096, 768, 768);
    gemm_k<EPI_VT><<<gDD, tb, 0, stream>>>(xn, WvT, bv, nullptr, nullptr, nullptr, VTx, 4096, 768, 768);
    gemm_k<EPI_QK><<<gDD, tb, 0, stream>>>(yn, WqdT, bqd, nullptr, nullptr, nullptr, Qy, 4096, 768, 768);
    gemm_k<EPI_QK><<<gDD, tb, 0, stream>>>(yn, WkdT, bkd, nullptr, nullptr, nullptr, Ky, 4096, 768, 768);
    gemm_k<EPI_VT><<<gDD, tb, 0, stream>>>(yn, WvdT, bvd, nullptr, nullptr, nullptr, VTy, 4096, 768, 768);
    // attention (4 configs)
    attn_k<<<4 * 48 * 16, tb, 0, stream>>>(Qx, Kx, VTx, Qy, Ky, VTy, csx, ccx, csy, ccy);
    // blends: csx = w11*csx + w12*ccx ; csy = w21*csy + w22*ccy
    int n8 = (int)(E / 8);
    blend_k<<<(n8 + 255) / 256, tb, 0, stream>>>(csx, ccx, w11, w12, n8);
    blend_k<<<(n8 + 255) / 256, tb, 0, stream>>>(csy, ccy, w21, w22, n8);
    // output projections + residual -> x1/y1 (f32)
    gemm_k<EPI_PLAIN><<<gDD, tb, 0, stream>>>(csx, WoT, bo, X, w11, w12, x1, 4096, 768, 768);
    gemm_k<EPI_PLAIN><<<gDD, tb, 0, stream>>>(csy, WodT, bod, Y, w21, w22, y1, 4096, 768, 768);
    // LN2 (f32 in -> bf16 out, reuse ccx/ccy)
    ln_k<<<4096, tb, 0, stream>>>(x1, l2xg, l2xb, ccx);
    ln_k<<<4096, tb, 0, stream>>>(y1, l2yg, l2yb, ccy);
    // MLP x
    dim3 gDF(48, 64), gFD(12, 64);
    gemm_k<EPI_GELU><<<gDF, tb, 0, stream>>>(ccx, W1T, b1, nullptr, nullptr, nullptr, h, 4096, 3072, 768);
    gemm_k<EPI_PLAIN><<<gFD, tb, 0, stream>>>(h, W2T, b2, x1, nullptr, nullptr, out_x, 4096, 768, 3072);
    // MLP y
    gemm_k<EPI_GELU><<<gDF, tb, 0, stream>>>(ccy, W1dT, b1d, nullptr, nullptr, nullptr, h, 4096, 3072, 768);
    gemm_k<EPI_PLAIN><<<gFD, tb, 0, stream>>>(h, W2dT, b2d, y1, nullptr, nullptr, out_y, 4096, 768, 3072);
}